// Round 7
// baseline (20.527 us; speedup 1.0000x reference)
//
#include <hip/hip_runtime.h>
#include <hip/hip_bf16.h>
#include <math.h>

#define EMBED 64
#define BATCH 16384
#define LDH 136        // h1s row stride in bf16 (272B, conflict-free b128)

typedef __attribute__((ext_vector_type(8))) short short8;  // bf16x8 MFMA A/B frag
typedef __attribute__((ext_vector_type(4))) float f32x4;   // MFMA C/D frag

__device__ inline void store_bf16x4(__hip_bfloat16* dst, float4 v) {
    __hip_bfloat16 tmp[4];
    tmp[0] = __float2bfloat16(v.x); tmp[1] = __float2bfloat16(v.y);
    tmp[2] = __float2bfloat16(v.z); tmp[3] = __float2bfloat16(v.w);
    *reinterpret_cast<ushort4*>(dst) = *reinterpret_cast<ushort4*>(tmp);
}

__device__ inline short8 load_w_bf16(const float* p) {
    const float4 lo = reinterpret_cast<const float4*>(p)[0];
    const float4 hi = reinterpret_cast<const float4*>(p)[1];
    __hip_bfloat16 tb[8];
    tb[0] = __float2bfloat16(lo.x); tb[1] = __float2bfloat16(lo.y);
    tb[2] = __float2bfloat16(lo.z); tb[3] = __float2bfloat16(lo.w);
    tb[4] = __float2bfloat16(hi.x); tb[5] = __float2bfloat16(hi.y);
    tb[6] = __float2bfloat16(hi.z); tb[7] = __float2bfloat16(hi.w);
    return *reinterpret_cast<short8*>(tb);
}

// ================= Kernel A: embeddings + attention -> X bf16 =================
// No LDS, no barriers. One wave = 4 batch elements (16 lanes x float4 each).
__global__ __launch_bounds__(256, 4) void gather_attn(
    const int* __restrict__ user, const int* __restrict__ item,
    const int* __restrict__ p1, const int* __restrict__ p2,
    const int* __restrict__ p3, const int* __restrict__ p4, const int* __restrict__ p5,
    const float* __restrict__ Wu, const float* __restrict__ bu,
    const float* __restrict__ Wi, const float* __restrict__ bi,
    __hip_bfloat16* __restrict__ Xb)
{
    const int t    = threadIdx.x;
    const int lane = t & 63;
    const int wv   = t >> 6;
    const int sub  = lane >> 4;        // element within wave (0..3)
    const int el   = lane & 15;        // float4 position within E=64
    const int gb   = blockIdx.x * 16 + wv * 4 + sub;

    const int iu = user[gb];
    const int ii = item[gb];
    int ip[5];
    ip[0] = p1[gb]; ip[1] = p2[gb]; ip[2] = p3[gb]; ip[3] = p4[gb]; ip[4] = p5[gb];

    const float4 bu4 = reinterpret_cast<const float4*>(bu)[el];
    const float4 bi4 = reinterpret_cast<const float4*>(bi)[el];

    // all 7 gathers issue in parallel (dwordx4 each)
    const float4 eu_r = reinterpret_cast<const float4*>(&Wu[(size_t)iu * EMBED])[el];
    const float4 ei_r = reinterpret_cast<const float4*>(&Wi[(size_t)ii * EMBED])[el];
    float4 ep[5];
    #pragma unroll
    for (int k = 0; k < 5; ++k)
        ep[k] = reinterpret_cast<const float4*>(&Wi[(size_t)ip[k] * EMBED])[el];

    float4 eu, ei;
    eu.x = fmaxf(eu_r.x + bu4.x, 0.0f); eu.y = fmaxf(eu_r.y + bu4.y, 0.0f);
    eu.z = fmaxf(eu_r.z + bu4.z, 0.0f); eu.w = fmaxf(eu_r.w + bu4.w, 0.0f);
    ei.x = fmaxf(ei_r.x + bi4.x, 0.0f); ei.y = fmaxf(ei_r.y + bi4.y, 0.0f);
    ei.z = fmaxf(ei_r.z + bi4.z, 0.0f); ei.w = fmaxf(ei_r.w + bi4.w, 0.0f);

    float w[5];
    #pragma unroll
    for (int k = 0; k < 5; ++k) {
        ep[k].x = fmaxf(ep[k].x + bi4.x, 0.0f);
        ep[k].y = fmaxf(ep[k].y + bi4.y, 0.0f);
        ep[k].z = fmaxf(ep[k].z + bi4.z, 0.0f);
        ep[k].w = fmaxf(ep[k].w + bi4.w, 0.0f);
        w[k] = ei.x * ep[k].x + ei.y * ep[k].y + ei.z * ep[k].z + ei.w * ep[k].w;
    }

    #pragma unroll
    for (int k = 0; k < 5; ++k) {
        float v = w[k];
        v += __shfl_xor(v, 1, 64);
        v += __shfl_xor(v, 2, 64);
        v += __shfl_xor(v, 4, 64);
        v += __shfl_xor(v, 8, 64);
        w[k] = v;
    }

    float m = w[0];
    #pragma unroll
    for (int k = 1; k < 5; ++k) m = fmaxf(m, w[k]);
    float z[5], s = 0.0f;
    #pragma unroll
    for (int k = 0; k < 5; ++k) { z[k] = expf(w[k] - m); s += z[k]; }
    const float scale = 0.2f / s;

    float4 pum = {0.0f, 0.0f, 0.0f, 0.0f};
    #pragma unroll
    for (int k = 0; k < 5; ++k) {
        pum.x += z[k] * ep[k].x; pum.y += z[k] * ep[k].y;
        pum.z += z[k] * ep[k].z; pum.w += z[k] * ep[k].w;
    }
    float4 pu;
    pu.x = eu.x + scale * pum.x; pu.y = eu.y + scale * pum.y;
    pu.z = eu.z + scale * pum.z; pu.w = eu.w + scale * pum.w;

    store_bf16x4(&Xb[(size_t)gb * 128 + el * 4], pu);
    store_bf16x4(&Xb[(size_t)gb * 128 + 64 + el * 4], ei);
}

// ================= Kernel B: 3-layer MLP via MFMA =================
// TB=32 rows/block (2 M-tiles), B-fragments loaded once per block.
__global__ __launch_bounds__(256, 2) void mlp_head(
    const __hip_bfloat16* __restrict__ Xb,
    const float* __restrict__ W1, const float* __restrict__ b1v,
    const float* __restrict__ W2, const float* __restrict__ b2v,
    const float* __restrict__ W3, const float* __restrict__ b3,
    float* __restrict__ out)
{
    __shared__ __align__(16) __hip_bfloat16 h1s[32 * LDH];
    __shared__ __align__(16) float          h2s[32 * 68];

    const int t    = threadIdx.x;
    const int lane = t & 63;
    const int wv   = t >> 6;
    const int fr   = lane & 15;    // A row / B col / C col
    const int kg   = lane >> 4;    // k-group
    const int bm   = blockIdx.x * 32;

    // ---------------- Layer 1 ----------------
    const int n0 = wv * 32;
    {
        short8 b1f[2][4];
        #pragma unroll
        for (int tile = 0; tile < 2; ++tile)
            #pragma unroll
            for (int kc = 0; kc < 4; ++kc)
                b1f[tile][kc] = load_w_bf16(&W1[(n0 + tile * 16 + fr) * 128 + kc * 32 + kg * 8]);

        const float bb0 = b1v[n0 + fr];
        const float bb1 = b1v[n0 + 16 + fr];

        #pragma unroll
        for (int mt = 0; mt < 2; ++mt) {
            short8 a[4];
            #pragma unroll
            for (int kc = 0; kc < 4; ++kc)
                a[kc] = *reinterpret_cast<const short8*>(
                    &Xb[(size_t)(bm + mt * 16 + fr) * 128 + kc * 32 + kg * 8]);

            f32x4 c0 = {bb0, bb0, bb0, bb0};
            f32x4 c1 = {bb1, bb1, bb1, bb1};
            #pragma unroll
            for (int kc = 0; kc < 4; ++kc) {
                c0 = __builtin_amdgcn_mfma_f32_16x16x32_bf16(a[kc], b1f[0][kc], c0, 0, 0, 0);
                c1 = __builtin_amdgcn_mfma_f32_16x16x32_bf16(a[kc], b1f[1][kc], c1, 0, 0, 0);
            }

            #pragma unroll
            for (int r = 0; r < 4; ++r) {
                const int row = mt * 16 + kg * 4 + r;
                h1s[row * LDH + n0 + fr]      = __float2bfloat16(fmaxf(c0[r], 0.0f));
                h1s[row * LDH + n0 + 16 + fr] = __float2bfloat16(fmaxf(c1[r], 0.0f));
            }
        }
    }

    __syncthreads();

    // ---------------- Layer 2 ----------------
    const int n2 = wv * 16;
    {
        short8 b2f[4];
        #pragma unroll
        for (int kc = 0; kc < 4; ++kc)
            b2f[kc] = load_w_bf16(&W2[(n2 + fr) * 128 + kc * 32 + kg * 8]);

        const float bb2 = b2v[n2 + fr];

        #pragma unroll
        for (int mt = 0; mt < 2; ++mt) {
            short8 a2[4];
            #pragma unroll
            for (int kc = 0; kc < 4; ++kc)
                a2[kc] = *reinterpret_cast<const short8*>(
                    &h1s[(mt * 16 + fr) * LDH + kc * 32 + kg * 8]);

            f32x4 c2 = {bb2, bb2, bb2, bb2};
            #pragma unroll
            for (int kc = 0; kc < 4; ++kc)
                c2 = __builtin_amdgcn_mfma_f32_16x16x32_bf16(a2[kc], b2f[kc], c2, 0, 0, 0);

            #pragma unroll
            for (int r = 0; r < 4; ++r)
                h2s[(mt * 16 + kg * 4 + r) * 68 + n2 + fr] = fmaxf(c2[r], 0.0f);
        }
    }

    __syncthreads();

    // ---------------- Layer 3 + sigmoid (all 4 waves, 8 rows each) ----------------
    {
        const int bl = wv * 8 + (lane >> 3);   // batch row 0..31
        const int q  = lane & 7;               // k-eighth (8 floats)
        const float4* w3p = reinterpret_cast<const float4*>(&W3[q * 8]);
        const float4* hp  = reinterpret_cast<const float4*>(&h2s[bl * 68 + q * 8]);
        const float4 w0 = w3p[0], w1 = w3p[1];
        const float4 h0 = hp[0],  h1 = hp[1];
        float acc = h0.x * w0.x + h0.y * w0.y + h0.z * w0.z + h0.w * w0.w
                  + h1.x * w1.x + h1.y * w1.y + h1.z * w1.z + h1.w * w1.w;
        acc += __shfl_xor(acc, 1, 64);
        acc += __shfl_xor(acc, 2, 64);
        acc += __shfl_xor(acc, 4, 64);
        if (q == 0)
            out[bm + bl] = 1.0f / (1.0f + expf(-(acc + b3[0])));
    }
}

extern "C" void kernel_launch(void* const* d_in, const int* in_sizes, int n_in,
                              void* d_out, int out_size, void* d_ws, size_t ws_size,
                              hipStream_t stream) {
    const int*   user = (const int*)  d_in[0];
    const int*   item = (const int*)  d_in[1];
    const int*   p1   = (const int*)  d_in[2];
    const int*   p2   = (const int*)  d_in[3];
    const int*   p3   = (const int*)  d_in[4];
    const int*   p4   = (const int*)  d_in[5];
    const int*   p5   = (const int*)  d_in[6];
    const float* Wu   = (const float*)d_in[7];
    const float* bu   = (const float*)d_in[8];
    const float* Wi   = (const float*)d_in[9];
    const float* bi   = (const float*)d_in[10];
    const float* W1   = (const float*)d_in[11];
    const float* b1   = (const float*)d_in[12];
    const float* W2   = (const float*)d_in[13];
    const float* b2   = (const float*)d_in[14];
    const float* W3   = (const float*)d_in[15];
    const float* b3   = (const float*)d_in[16];
    float* out = (float*)d_out;

    __hip_bfloat16* Xb = (__hip_bfloat16*)d_ws;   // 16384 x 128 bf16 = 4 MB

    hipLaunchKernelGGL(gather_attn, dim3(BATCH / 16), dim3(256), 0, stream,
                       user, item, p1, p2, p3, p4, p5, Wu, bu, Wi, bi, Xb);

    hipLaunchKernelGGL(mlp_head, dim3(BATCH / 32), dim3(256), 0, stream,
                       Xb, W1, b1, W2, b2, W3, b3, out);
}